// Round 4
// baseline (4709.117 us; speedup 1.0000x reference)
//
#include <hip/hip_runtime.h>
#include <cstdint>
#include <cstddef>

typedef _Float16 f16;
typedef _Float16 f16x4 __attribute__((ext_vector_type(4)));
typedef _Float16 f16x8 __attribute__((ext_vector_type(8)));
typedef float f32x4 __attribute__((ext_vector_type(4)));

#define HDIM 1024
#define TAI 8

// ---------------------------------------------------------------------------
// Job descriptor for the generic MFMA GEMM (C = A @ B^T-stored-weights [+res])
// A modes: 0 = raw f32, 1 = f32 with deferred-LN applied at staging, 2 = f16
// EPI:     0 = f16 store * scale, 1 = f32 store of acc+res, + row-stat atomics
// RESMODE: 0 = raw f32 residual, 1 = LN-applied residual
// ---------------------------------------------------------------------------
struct Job {
  const void* A;
  const float* Ast;   // per-row (sum,sumsq) for A's deferred LN
  const float* Ag;    // LN gamma (per column/feature of A)
  const float* Abt;   // LN beta
  const f16*  BT;     // weights, transposed [N][K] fp16
  void* C;
  const float* Res;   // residual source (f32)
  const float* Rst;   // residual LN stats
  const float* Rg;
  const float* Rbt;
  float* Ost;         // output row-stats (atomicAdd sum,sumsq), may be null
  float scale;
};
struct JobPack { Job j[8]; };
static_assert(sizeof(JobPack) <= 4096, "kernarg too big");

__device__ __forceinline__ void ln_params(const float* st, int row, float& mean, float& rstd){
  float s = st[row*2+0], q = st[row*2+1];
  mean = s * (1.0f/1024.0f);
  float var = q * (1.0f/1024.0f) - mean*mean;
  rstd = rsqrtf(var + 1e-5f);
}

// ---------------------------------------------------------------------------
// Generic 1024-K MFMA GEMM. Block tile BM x BN, BK=64, 4 waves (2x2),
// wave tile (BM/2)x(BN/2) built from 16x16x32 f16 MFMAs.
// LDS tiles padded to 72 halves/row: ds_read_b128-aligned, 2-way-conflict only
// (2-way is free per m136).
// ---------------------------------------------------------------------------
template<int BM,int BN,int AMODE,int EPI,int RESMODE>
__global__ __launch_bounds__(256)
void gemm_k(JobPack jp){
  const Job jb = jp.j[blockIdx.z];
  constexpr int MI = BM/32, NI = BN/32;
  __shared__ f16 As[BM][72];
  __shared__ f16 Bs[BN][72];
  const int tid = threadIdx.x;
  const int lane = tid & 63;
  const int wv = tid >> 6;
  const int wm = wv >> 1, wn = wv & 1;
  const int r0 = blockIdx.y * BM, c0 = blockIdx.x * BN;

  f32x4 acc[MI][NI];
  const f32x4 fz = {0.f,0.f,0.f,0.f};
#pragma unroll
  for (int a=0;a<MI;a++)
#pragma unroll
    for (int b=0;b<NI;b++) acc[a][b] = fz;

  for (int k0 = 0; k0 < HDIM; k0 += 64){
    // ---- stage A (BM x 64) ----
    if constexpr (AMODE == 2){
      const f16* Af = (const f16*)jb.A;
#pragma unroll
      for (int p=0;p<BM/32;p++){
        int row = (tid>>3) + p*32, ch = tid & 7;
        uint4 v = *(const uint4*)(Af + (size_t)(r0+row)*HDIM + k0 + ch*8);
        *(uint4*)&As[row][ch*8] = v;
      }
    } else {
      const float* Af = (const float*)jb.A;
#pragma unroll
      for (int p=0;p<BM/16;p++){
        int row = (tid>>4) + p*16;
        int c4 = (tid & 15)*4;
        float4 v = *(const float4*)(Af + (size_t)(r0+row)*HDIM + k0 + c4);
        if constexpr (AMODE == 1){
          float mean,rstd; ln_params(jb.Ast, r0+row, mean, rstd);
          float4 g = *(const float4*)(jb.Ag  + k0 + c4);
          float4 bb= *(const float4*)(jb.Abt + k0 + c4);
          v.x = (v.x-mean)*rstd*g.x + bb.x;
          v.y = (v.y-mean)*rstd*g.y + bb.y;
          v.z = (v.z-mean)*rstd*g.z + bb.z;
          v.w = (v.w-mean)*rstd*g.w + bb.w;
        }
        f16x4 hv = { (f16)v.x, (f16)v.y, (f16)v.z, (f16)v.w };
        *(f16x4*)&As[row][c4] = hv;
      }
    }
    // ---- stage B (BN x 64) from fp16 transposed weights ----
#pragma unroll
    for (int p=0;p<BN/32;p++){
      int row = (tid>>3) + p*32, ch = tid & 7;
      uint4 v = *(const uint4*)(jb.BT + (size_t)(c0+row)*HDIM + k0 + ch*8);
      *(uint4*)&Bs[row][ch*8] = v;
    }
    __syncthreads();
#pragma unroll
    for (int kk=0;kk<2;kk++){
      f16x8 af[MI], bf[NI];
#pragma unroll
      for (int mi=0;mi<MI;mi++)
        af[mi] = *(const f16x8*)&As[wm*(BM/2)+mi*16+(lane&15)][kk*32 + 8*(lane>>4)];
#pragma unroll
      for (int ni=0;ni<NI;ni++)
        bf[ni] = *(const f16x8*)&Bs[wn*(BN/2)+ni*16+(lane&15)][kk*32 + 8*(lane>>4)];
#pragma unroll
      for (int mi=0;mi<MI;mi++)
#pragma unroll
        for (int ni=0;ni<NI;ni++)
          acc[mi][ni] = __builtin_amdgcn_mfma_f32_16x16x32_f16(af[mi], bf[ni], acc[mi][ni], 0,0,0);
    }
    __syncthreads();
  }

  if constexpr (EPI == 0){
    f16* C = (f16*)jb.C;
    const float sc = jb.scale;
#pragma unroll
    for (int mi=0;mi<MI;mi++)
#pragma unroll
      for (int ni=0;ni<NI;ni++)
#pragma unroll
        for (int r=0;r<4;r++){
          int row = r0 + wm*(BM/2) + mi*16 + 4*(lane>>4) + r;
          int col = c0 + wn*(BN/2) + ni*16 + (lane&15);
          C[(size_t)row*HDIM + col] = (f16)(acc[mi][ni][r] * sc);
        }
  } else {
    float* C = (float*)jb.C;
#pragma unroll
    for (int mi=0;mi<MI;mi++)
#pragma unroll
      for (int r=0;r<4;r++){
        int row = r0 + wm*(BM/2) + mi*16 + 4*(lane>>4) + r;
        float rmean=0.f, rrstd=0.f;
        if constexpr (RESMODE == 1){ ln_params(jb.Rst, row, rmean, rrstd); }
        float sv = 0.f, sq = 0.f;
#pragma unroll
        for (int ni=0;ni<NI;ni++){
          int col = c0 + wn*(BN/2) + ni*16 + (lane&15);
          float rv = jb.Res[(size_t)row*HDIM + col];
          if constexpr (RESMODE == 1) rv = (rv - rmean)*rrstd*jb.Rg[col] + jb.Rbt[col];
          float v = acc[mi][ni][r] + rv;
          C[(size_t)row*HDIM + col] = v;
          sv += v; sq += v*v;
        }
#pragma unroll
        for (int m=1;m<16;m<<=1){ sv += __shfl_xor(sv, m); sq += __shfl_xor(sq, m); }
        if ((lane & 15) == 0){
          atomicAdd(&jb.Ost[row*2+0], sv);
          atomicAdd(&jb.Ost[row*2+1], sq);
        }
      }
  }
}

// ---------------------------------------------------------------------------
// Attention: one wave per (batch, head). 32x32 scores via 16x16x32 MFMA,
// masked softmax over k<L (invalid q rows produce exact zeros, matching
// m1/m2 semantics), then P@V with V transposed in LDS.
// ---------------------------------------------------------------------------
__global__ __launch_bounds__(64)
void attn_k(const f16* __restrict__ Q, const f16* __restrict__ K, const f16* __restrict__ V,
            f16* __restrict__ O, int L){
  __shared__ f16 Qs[32][72], Ks[32][72];
  __shared__ f16 Vt[64][56];
  __shared__ float S[32][33];
  __shared__ f16 Ps[32][56];
  const int l = threadIdx.x;
  const int b = blockIdx.x >> 4, hd = blockIdx.x & 15;
  {
    int row = l >> 1;
    int base = (l & 1) * 32;
#pragma unroll
    for (int v=0; v<4; v++){
      int off = base + v*8;
      *(uint4*)&Qs[row][off] = *(const uint4*)(Q + (size_t)(b*32+row)*HDIM + hd*64 + off);
      *(uint4*)&Ks[row][off] = *(const uint4*)(K + (size_t)(b*32+row)*HDIM + hd*64 + off);
    }
  }
  {
    int kk = l & 31, d0 = (l>>5)*32;
    f16 tmp[32];
    const uint4* vs = (const uint4*)(V + (size_t)(b*32+kk)*HDIM + hd*64 + d0);
    *(uint4*)&tmp[0]  = vs[0];
    *(uint4*)&tmp[8]  = vs[1];
    *(uint4*)&tmp[16] = vs[2];
    *(uint4*)&tmp[24] = vs[3];
#pragma unroll
    for (int jj=0;jj<32;jj++) Vt[d0+jj][kk] = tmp[jj];
  }
  __syncthreads();
  const f32x4 fz = {0.f,0.f,0.f,0.f};
  f32x4 sc[2][2];
#pragma unroll
  for (int a=0;a<2;a++)
#pragma unroll
    for (int c=0;c<2;c++) sc[a][c] = fz;
#pragma unroll
  for (int ks=0;ks<2;ks++){
    f16x8 qa[2], kb[2];
#pragma unroll
    for (int ti=0;ti<2;ti++) qa[ti]=*(const f16x8*)&Qs[16*ti+(l&15)][ks*32+8*(l>>4)];
#pragma unroll
    for (int tj=0;tj<2;tj++) kb[tj]=*(const f16x8*)&Ks[16*tj+(l&15)][ks*32+8*(l>>4)];
#pragma unroll
    for (int ti=0;ti<2;ti++)
#pragma unroll
      for (int tj=0;tj<2;tj++)
        sc[ti][tj]=__builtin_amdgcn_mfma_f32_16x16x32_f16(qa[ti],kb[tj],sc[ti][tj],0,0,0);
  }
#pragma unroll
  for (int ti=0;ti<2;ti++)
#pragma unroll
    for (int tj=0;tj<2;tj++)
#pragma unroll
      for (int r=0;r<4;r++)
        S[16*ti+4*(l>>4)+r][16*tj+(l&15)] = sc[ti][tj][r];
  __syncthreads();
  {
    int q = l & 31, ch = (l>>5)*16;
    bool vq = q < L;
    float mx = -3.0e38f;
#pragma unroll
    for (int c=0;c<16;c++){ int k=ch+c; if (k<L) mx = fmaxf(mx, S[q][k]); }
    mx = fmaxf(mx, __shfl_xor(mx, 32));
    float e[16]; float sum=0.f;
#pragma unroll
    for (int c=0;c<16;c++){
      int k=ch+c;
      float ev = (vq && k<L) ? __expf(S[q][k]-mx) : 0.0f;
      e[c]=ev; sum+=ev;
    }
    sum += __shfl_xor(sum, 32);
    float inv = vq ? (1.0f/sum) : 0.0f;
#pragma unroll
    for (int c=0;c<16;c++) Ps[q][ch+c] = (f16)(e[c]*inv);
  }
  __syncthreads();
  {
    f16x8 pa[2], vb[4];
#pragma unroll
    for (int ti=0;ti<2;ti++) pa[ti]=*(const f16x8*)&Ps[16*ti+(l&15)][8*(l>>4)];
#pragma unroll
    for (int tj=0;tj<4;tj++) vb[tj]=*(const f16x8*)&Vt[16*tj+(l&15)][8*(l>>4)];
    const f32x4 fz2 = {0.f,0.f,0.f,0.f};
#pragma unroll
    for (int ti=0;ti<2;ti++)
#pragma unroll
      for (int tj=0;tj<4;tj++){
        f32x4 o = __builtin_amdgcn_mfma_f32_16x16x32_f16(pa[ti],vb[tj],fz2,0,0,0);
#pragma unroll
        for (int r=0;r<4;r++){
          int row = b*32 + 16*ti + 4*(l>>4) + r;
          int col = hd*64 + 16*tj + (l&15);
          O[(size_t)row*HDIM + col] = (f16)o[r];
        }
      }
  }
}

// ---------------------------------------------------------------------------
// Skinny hf @ Wso GEMM: M=32 (batch), K=32768 (flattened LN-applied h3),
// N=512, split-K 64-way into partials[64][32][512].
// ---------------------------------------------------------------------------
__global__ __launch_bounds__(256)
void wso_k(const float* __restrict__ X, const float* __restrict__ st,
           const float* __restrict__ g, const float* __restrict__ bt,
           const float* __restrict__ Wso, float* __restrict__ partials){
  __shared__ f16 As[32][72];
  __shared__ f16 Bs[64][72];
  const int tid=threadIdx.x, lane=tid&63, wv=tid>>6;
  const int wm=wv>>1, wn=wv&1;
  const int n0 = blockIdx.x*64;
  const int kb = blockIdx.y;
  const f32x4 fz = {0.f,0.f,0.f,0.f};
  f32x4 acc0=fz, acc1=fz;
  for (int s8=0;s8<8;s8++){
    int kg0 = kb*512 + s8*64;
    int tt = kg0 >> 10, cb = kg0 & 1023;
#pragma unroll
    for (int p=0;p<2;p++){
      int brow=(tid>>4)+p*16, c4=(tid&15)*4;
      int grow = brow*32+tt;
      float4 v = *(const float4*)(X + (size_t)grow*HDIM + cb + c4);
      float mean,rstd; ln_params(st, grow, mean, rstd);
      float4 gg = *(const float4*)(g  + cb + c4);
      float4 bb = *(const float4*)(bt + cb + c4);
      v.x=(v.x-mean)*rstd*gg.x+bb.x;
      v.y=(v.y-mean)*rstd*gg.y+bb.y;
      v.z=(v.z-mean)*rstd*gg.z+bb.z;
      v.w=(v.w-mean)*rstd*gg.w+bb.w;
      f16x4 hv={(f16)v.x,(f16)v.y,(f16)v.z,(f16)v.w};
      *(f16x4*)&As[brow][c4]=hv;
    }
#pragma unroll
    for (int p=0;p<4;p++){
      int kk=(tid>>4)+p*16, n4=(tid&15)*4;
      float4 v = *(const float4*)(Wso + (size_t)(kg0+kk)*512 + n0 + n4);
      Bs[n4+0][kk]=(f16)v.x; Bs[n4+1][kk]=(f16)v.y;
      Bs[n4+2][kk]=(f16)v.z; Bs[n4+3][kk]=(f16)v.w;
    }
    __syncthreads();
#pragma unroll
    for (int kk2=0;kk2<2;kk2++){
      f16x8 a0=*(const f16x8*)&As[wm*16+(lane&15)][kk2*32+8*(lane>>4)];
      f16x8 b0=*(const f16x8*)&Bs[wn*32+ 0+(lane&15)][kk2*32+8*(lane>>4)];
      f16x8 b1=*(const f16x8*)&Bs[wn*32+16+(lane&15)][kk2*32+8*(lane>>4)];
      acc0=__builtin_amdgcn_mfma_f32_16x16x32_f16(a0,b0,acc0,0,0,0);
      acc1=__builtin_amdgcn_mfma_f32_16x16x32_f16(a0,b1,acc1,0,0,0);
    }
    __syncthreads();
  }
#pragma unroll
  for (int r=0;r<4;r++){
    int brow = wm*16 + 4*(lane>>4) + r;
    int c_0 = n0 + wn*32 + 0 + (lane&15);
    int c_1 = n0 + wn*32 + 16 + (lane&15);
    partials[(size_t)kb*16384 + brow*512 + c_0] = acc0[r];
    partials[(size_t)kb*16384 + brow*512 + c_1] = acc1[r];
  }
}

// ---------------------------------------------------------------------------
// Readout: reduce Wso partials -> relu -> out + sbuf ; r = sigmoid(hf @ Wr).
// ---------------------------------------------------------------------------
__global__ __launch_bounds__(256)
void readout_k(const float* __restrict__ partials, const float* __restrict__ X,
               const float* __restrict__ st, const float* __restrict__ g, const float* __restrict__ bt,
               const float* __restrict__ Wr, float* __restrict__ out, float* __restrict__ sbuf, int iter){
  const int b = blockIdx.x, t = threadIdx.x;
#pragma unroll
  for (int cc=0;cc<2;cc++){
    int c = t + cc*256;
    float s = 0.f;
    for (int ks=0;ks<64;ks++) s += partials[(size_t)ks*16384 + b*512 + c];
    s = fmaxf(s, 0.f);
    out[256 + (size_t)(b*TAI + iter)*512 + c] = s;
    sbuf[b*512 + c] = s;
  }
  float accr = 0.f;
  for (int kk = t; kk < 32768; kk += 256){
    int tt = kk >> 10, c = kk & 1023;
    int row = b*32 + tt;
    float mean,rstd; ln_params(st, row, mean, rstd);
    float x = (X[(size_t)row*HDIM + c]-mean)*rstd*g[c]+bt[c];
    accr += x * Wr[kk];
  }
  __shared__ float red[256];
  red[t]=accr; __syncthreads();
  for (int ss=128; ss>0; ss>>=1){ if (t<ss) red[t]+=red[t+ss]; __syncthreads(); }
  if (t==0) out[b*TAI + iter] = 1.0f/(1.0f+__expf(-red[0]));
}

// ---------------------------------------------------------------------------
// h0 = tokens + pe (valid rows), inline action-embed for row pos_a
// (also persists the action row into tokens). Invalid rows exactly zero.
// ---------------------------------------------------------------------------
__global__ __launch_bounds__(256)
void h0_k(float* __restrict__ tokens, const float* __restrict__ pe,
          const float* __restrict__ a_list, const float* __restrict__ Wa,
          float* __restrict__ h0, int iter){
  const int r = blockIdx.x;
  const int b = r >> 5, t5 = r & 31;
  const int pos_a = 17 + 2*iter, L = pos_a + 1;
  const int c4 = threadIdx.x * 4;
  if (t5 >= L){
    float4 z = make_float4(0.f,0.f,0.f,0.f);
    *(float4*)&h0[(size_t)r*HDIM + c4] = z;
    return;
  }
  if (t5 == pos_a){
    __shared__ float al[64];
    if (threadIdx.x < 64) al[threadIdx.x] = a_list[(size_t)(b*TAI + iter)*64 + threadIdx.x];
    __syncthreads();
    float s0=0.f,s1=0.f,s2=0.f,s3=0.f;
    for (int k=0;k<64;k++){
      float av = al[k];
      const float* wr = Wa + (size_t)k*HDIM + c4;
      s0 += av*wr[0]; s1 += av*wr[1]; s2 += av*wr[2]; s3 += av*wr[3];
    }
    s0=fmaxf(s0,0.f); s1=fmaxf(s1,0.f); s2=fmaxf(s2,0.f); s3=fmaxf(s3,0.f);
    *(float4*)&tokens[(size_t)r*HDIM + c4] = make_float4(s0,s1,s2,s3);
    const float4 pv = *(const float4*)&pe[(size_t)t5*HDIM + c4];
    *(float4*)&h0[(size_t)r*HDIM + c4] = make_float4(s0+pv.x, s1+pv.y, s2+pv.z, s3+pv.w);
  } else {
    const float4 tv = *(const float4*)&tokens[(size_t)r*HDIM + c4];
    const float4 pv = *(const float4*)&pe[(size_t)t5*HDIM + c4];
    *(float4*)&h0[(size_t)r*HDIM + c4] = make_float4(tv.x+pv.x, tv.y+pv.y, tv.z+pv.z, tv.w+pv.w);
  }
}

// ---------------------------------------------------------------------------
// Small fp32 embed GEMM: out[row_map(ar)] = relu(A[ar] @ W), K<=512, N=1024.
// 8 A-rows staged in LDS per block; grid.y splits columns (256 each).
// row map: orow = (ar/tpg)*32 + (ar%tpg)*str + off
// ---------------------------------------------------------------------------
__global__ __launch_bounds__(256)
void embed_k(const float* __restrict__ A, int K, const float* __restrict__ W,
             float* __restrict__ outb, int tpg, int str, int off){
  __shared__ float as[8][512];
  const int r0 = blockIdx.x*8;
  const int t = threadIdx.x;
  for (int rr=0;rr<8;rr++)
    for (int k=t;k<K;k+=256) as[rr][k] = A[(size_t)(r0+rr)*K + k];
  __syncthreads();
  const int c = blockIdx.y*256 + t;
  float acc[8];
#pragma unroll
  for (int rr=0;rr<8;rr++) acc[rr]=0.f;
  for (int k=0;k<K;k++){
    float wv = W[(size_t)k*HDIM + c];
#pragma unroll
    for (int rr=0;rr<8;rr++) acc[rr] += as[rr][k]*wv;
  }
#pragma unroll
  for (int rr=0;rr<8;rr++){
    int ar = r0+rr;
    int orow = (ar/tpg)*32 + (ar%tpg)*str + off;
    outb[(size_t)orow*HDIM + c] = fmaxf(acc[rr], 0.f);
  }
}

// ---------------------------------------------------------------------------
// fp32 [K][N] -> fp16 [N][K] transpose-convert (per-z matrix of K*N elems)
// ---------------------------------------------------------------------------
__global__ __launch_bounds__(256)
void transp_k(const float* __restrict__ in, f16* __restrict__ outp, int K, int N){
  __shared__ float tile[32][33];
  const int n0 = blockIdx.x*32, k0 = blockIdx.y*32;
  const float* ip = in + (size_t)blockIdx.z*K*N;
  f16* op = outp + (size_t)blockIdx.z*K*N;
  const int tx = threadIdx.x & 31, ty = threadIdx.x >> 5;
#pragma unroll
  for (int p=0;p<4;p++){ int kk=ty+p*8; tile[kk][tx] = ip[(size_t)(k0+kk)*N + n0+tx]; }
  __syncthreads();
#pragma unroll
  for (int p=0;p<4;p++){ int nn=ty+p*8; op[(size_t)(n0+nn)*K + k0+tx] = (f16)tile[tx][nn]; }
}

// positional encoding, fp64 math to match numpy reference bit-closely
__global__ __launch_bounds__(256)
void pe_k(float* __restrict__ pe){
  int idx = blockIdx.x*256 + threadIdx.x;
  int t = idx >> 10, ii = idx & 1023;
  double ang = (double)t / pow(10000.0, (double)(2*(ii/2)) / 1024.0);
  pe[idx] = (float)(((ii & 1)==0) ? sin(ang) : cos(ang));
}

// ---------------------------------------------------------------------------
extern "C" void kernel_launch(void* const* d_in, const int* in_sizes, int n_in,
                              void* d_out, int out_size, void* d_ws, size_t ws_size,
                              hipStream_t stream){
  (void)in_sizes; (void)n_in; (void)out_size; (void)ws_size;
  const float* hist_s=(const float*)d_in[0];
  const float* hist_a=(const float*)d_in[1];
  const float* s_in  =(const float*)d_in[2];
  const float* a_list=(const float*)d_in[3];
  const float* Ws =(const float*)d_in[4];
  const float* Wa =(const float*)d_in[5];
  const float* Wq =(const float*)d_in[6];
  const float* Wk =(const float*)d_in[7];
  const float* Wv =(const float*)d_in[8];
  const float* Wo =(const float*)d_in[9];
  const float* Wfc=(const float*)d_in[10];
  const float* ln1g=(const float*)d_in[11];
  const float* ln1b=(const float*)d_in[12];
  const float* ln2g=(const float*)d_in[13];
  const float* ln2b=(const float*)d_in[14];
  const float* Wr =(const float*)d_in[15];
  const float* Wso=(const float*)d_in[16];
  float* out=(float*)d_out;

  char* wp=(char*)d_ws;
  auto alloc=[&](size_t bytes)->char*{ char* p=wp; wp += (bytes + 255) & ~(size_t)255; return p; };
  const size_t MB = 1024*1024;
  const size_t MM = 1024*1024; // elements per 1024x1024 matrix

  float* tokens =(float*)alloc(4*MB);               // zeroed
  float* stats  =(float*)alloc(64*2048*sizeof(float)); // zeroed (64 LN instances)
  float* pe     =(float*)alloc(32*1024*sizeof(float));
  float* h0     =(float*)alloc(4*MB);
  float* hout[4]; for(int j=0;j<4;j++) hout[j]=(float*)alloc(4*MB);
  float* x1     =(float*)alloc(4*MB);
  f16* Q16[4]; for(int j=0;j<4;j++) Q16[j]=(f16*)alloc(2*MB);
  f16* K16[4]; for(int j=0;j<4;j++) K16[j]=(f16*)alloc(2*MB);
  f16* V16 =(f16*)alloc(2*MB);
  f16* AT16=(f16*)alloc(2*MB);
  f16* WqT =(f16*)alloc(8*MB);
  f16* WkT =(f16*)alloc(8*MB);
  f16* WvT =(f16*)alloc(8*MB);
  f16* WoT =(f16*)alloc(8*MB);
  f16* WfcT=(f16*)alloc(8*MB);
  float* partials=(float*)alloc((size_t)64*32*512*sizeof(float));
  float* sbuf=(float*)alloc(32*512*sizeof(float));

  // zero tokens + stats (contiguous)
  hipMemsetAsync(tokens, 0, (size_t)((char*)pe - (char*)tokens), stream);

  pe_k<<<128,256,0,stream>>>(pe);
  transp_k<<<dim3(32,32,4),256,0,stream>>>(Wq,  WqT, 1024,1024);
  transp_k<<<dim3(32,32,4),256,0,stream>>>(Wk,  WkT, 1024,1024);
  transp_k<<<dim3(32,32,4),256,0,stream>>>(Wv,  WvT, 1024,1024);
  transp_k<<<dim3(32,32,4),256,0,stream>>>(Wo,  WoT, 1024,1024);
  transp_k<<<dim3(32,32,4),256,0,stream>>>(Wfc, WfcT,1024,1024);
  embed_k<<<dim3(32,4),256,0,stream>>>(hist_s,512,Ws,tokens,8,2,0);
  embed_k<<<dim3(32,4),256,0,stream>>>(hist_a, 64,Wa,tokens,8,2,1);
  embed_k<<<dim3(4,4),256,0,stream>>>(s_in,  512,Ws,tokens,1,0,16);

  auto st1=[&](int i,int j)->float*{ return stats + ((size_t)(i*4+j)*2+0)*2048; };
  auto st2=[&](int i,int j)->float*{ return stats + ((size_t)(i*4+j)*2+1)*2048; };

  auto mkj=[&](const void*A,const float*Ast,const float*Ag,const float*Abt,
               const f16*BT,void*C,float scale)->Job{
    Job q{}; q.A=A; q.Ast=Ast; q.Ag=Ag; q.Abt=Abt; q.BT=BT; q.C=C; q.scale=scale; return q;
  };
  auto mkj2=[&](const void*A,const float*Ast,const float*Ag,const float*Abt,
                const f16*BT,void*C,const float*Res,const float*Rst,const float*Rg,
                const float*Rbt,float*Ost)->Job{
    Job q{}; q.A=A; q.Ast=Ast; q.Ag=Ag; q.Abt=Abt; q.BT=BT; q.C=C;
    q.Res=Res; q.Rst=Rst; q.Rg=Rg; q.Rbt=Rbt; q.Ost=Ost; q.scale=1.f; return q;
  };

  for (int i=0;i<8;i++){
    const int pos_a = 17 + 2*i, L = pos_a + 1;
    h0_k<<<1024,256,0,stream>>>(tokens, pe, a_list, Wa, h0, i);

    if (i>0){
      // hoisted Q,K for all 4 layers from prev_h (LN2 of previous iteration)
      JobPack jp{};
      for (int j=0;j<4;j++){
        jp.j[2*j+0]=mkj(hout[j], st2(i-1,j), ln2g+j*1024, ln2b+j*1024,
                        WqT+(size_t)j*MM, Q16[j], 0.125f);
        jp.j[2*j+1]=mkj(hout[j], st2(i-1,j), ln2g+j*1024, ln2b+j*1024,
                        WkT+(size_t)j*MM, K16[j], 1.0f);
      }
      gemm_k<128,128,1,0,0><<<dim3(8,8,8),256,0,stream>>>(jp);
    }

    for (int j=0;j<4;j++){
      const float* Ain  = (j==0)? h0 : hout[j-1];
      const float* Ast  = (j==0)? nullptr : st2(i,j-1);
      const float* Ag   = (j==0)? nullptr : ln2g+(j-1)*1024;
      const float* Abt  = (j==0)? nullptr : ln2b+(j-1)*1024;

      if (i==0){
        JobPack jp{};
        jp.j[0]=mkj(Ain,Ast,Ag,Abt, WqT+(size_t)j*MM, Q16[j], 0.125f);
        jp.j[1]=mkj(Ain,Ast,Ag,Abt, WkT+(size_t)j*MM, K16[j], 1.0f);
        jp.j[2]=mkj(Ain,Ast,Ag,Abt, WvT+(size_t)j*MM, V16,    1.0f);
        if (j==0) gemm_k<128,128,0,0,0><<<dim3(8,8,3),256,0,stream>>>(jp);
        else      gemm_k<128,128,1,0,0><<<dim3(8,8,3),256,0,stream>>>(jp);
      } else {
        JobPack jp{};
        jp.j[0]=mkj(Ain,Ast,Ag,Abt, WvT+(size_t)j*MM, V16, 1.0f);
        if (j==0) gemm_k<64,64,0,0,0><<<dim3(16,16,1),256,0,stream>>>(jp);
        else      gemm_k<64,64,1,0,0><<<dim3(16,16,1),256,0,stream>>>(jp);
      }

      attn_k<<<512,64,0,stream>>>(Q16[j], K16[j], V16, AT16, L);

      { // Wo projection + residual(h_in) + LN1 stats
        JobPack jo{};
        jo.j[0]=mkj2(AT16, nullptr,nullptr,nullptr, WoT+(size_t)j*MM, x1,
                     Ain, Ast, Ag, Abt, st1(i,j));
        if (j==0) gemm_k<64,64,2,1,0><<<dim3(16,16,1),256,0,stream>>>(jo);
        else      gemm_k<64,64,2,1,1><<<dim3(16,16,1),256,0,stream>>>(jo);
      }
      { // FC + residual(LN1(x1)) + LN2 stats
        JobPack jf{};
        jf.j[0]=mkj2(x1, st1(i,j), ln1g+j*1024, ln1b+j*1024, WfcT+(size_t)j*MM, hout[j],
                     x1, st1(i,j), ln1g+j*1024, ln1b+j*1024, st2(i,j));
        gemm_k<64,64,1,1,1><<<dim3(16,16,1),256,0,stream>>>(jf);
      }
    }

    wso_k<<<dim3(8,64),256,0,stream>>>(hout[3], st2(i,3), ln2g+3*1024, ln2b+3*1024, Wso, partials);
    readout_k<<<32,256,0,stream>>>(partials, hout[3], st2(i,3), ln2g+3*1024, ln2b+3*1024,
                                   Wr, out, sbuf, i);
    if (i < 7){ // i==7 write would be tokens[:,32] -> dropped in reference (OOB)
      embed_k<<<dim3(4,4),256,0,stream>>>(sbuf, 512, Ws, tokens, 1, 0, pos_a+1);
    }
  }
}

// Round 9
// 3448.886 us; speedup vs baseline: 1.3654x; 1.3654x over previous
//
#include <hip/hip_runtime.h>
#include <cstdint>
#include <cstddef>

typedef _Float16 f16;
typedef _Float16 f16x4 __attribute__((ext_vector_type(4)));
typedef _Float16 f16x8 __attribute__((ext_vector_type(8)));
typedef float f32x4 __attribute__((ext_vector_type(4)));

#define HDIM 1024
#define TAI 8

// ---------------------------------------------------------------------------
// Job descriptor for the MFMA GEMMs (C = A @ B^T-stored-weights [+res])
// A modes: 0 = raw f32, 1 = f32 with deferred-LN applied at staging, 2 = f16
// EPI:     0 = f16 store * scale, 1 = f32 store of acc+res, + row-stat atomics
// RESMODE: 0 = raw f32 residual, 1 = LN-applied residual
// ---------------------------------------------------------------------------
struct Job {
  const void* A;
  const float* Ast;   // per-row (sum,sumsq) for A's deferred LN
  const float* Ag;    // LN gamma
  const float* Abt;   // LN beta
  const f16*  BT;     // weights, transposed [N][K] fp16
  void* C;
  const float* Res;   // residual source (f32)
  const float* Rst;   // residual LN stats
  const float* Rg;
  const float* Rbt;
  float* Ost;         // output row-stats (atomicAdd sum,sumsq)
  float scale;
};
struct JobPack { Job j[8]; };
static_assert(sizeof(JobPack) <= 4096, "kernarg too big");

__device__ __forceinline__ void ln_params(const float* st, int row, float& mean, float& rstd){
  float s = st[row*2+0], q = st[row*2+1];
  mean = s * (1.0f/1024.0f);
  float var = q * (1.0f/1024.0f) - mean*mean;
  rstd = rsqrtf(var + 1e-5f);
}

// ---------------------------------------------------------------------------
// 128x128-tile GEMM, 256 thr, 4 waves (2x2) — used only for the batched (z=8)
// hoisted Q/K projections where the grid is already 512 blocks.
// ---------------------------------------------------------------------------
template<int BM,int BN,int AMODE,int EPI,int RESMODE>
__global__ __launch_bounds__(256)
void gemm_k(JobPack jp){
  const Job jb = jp.j[blockIdx.z];
  constexpr int MI = BM/32, NI = BN/32;
  __shared__ f16 As[BM][72];
  __shared__ f16 Bs[BN][72];
  const int tid = threadIdx.x;
  const int lane = tid & 63;
  const int wv = tid >> 6;
  const int wm = wv >> 1, wn = wv & 1;
  const int r0 = blockIdx.y * BM, c0 = blockIdx.x * BN;

  f32x4 acc[MI][NI];
  const f32x4 fz = {0.f,0.f,0.f,0.f};
#pragma unroll
  for (int a=0;a<MI;a++)
#pragma unroll
    for (int b=0;b<NI;b++) acc[a][b] = fz;

  for (int k0 = 0; k0 < HDIM; k0 += 64){
    if constexpr (AMODE == 2){
      const f16* Af = (const f16*)jb.A;
#pragma unroll
      for (int p=0;p<BM/32;p++){
        int row = (tid>>3) + p*32, ch = tid & 7;
        *(uint4*)&As[row][ch*8] = *(const uint4*)(Af + (size_t)(r0+row)*HDIM + k0 + ch*8);
      }
    } else {
      const float* Af = (const float*)jb.A;
#pragma unroll
      for (int p=0;p<BM/16;p++){
        int row = (tid>>4) + p*16;
        int c4 = (tid & 15)*4;
        float4 v = *(const float4*)(Af + (size_t)(r0+row)*HDIM + k0 + c4);
        if constexpr (AMODE == 1){
          float mean,rstd; ln_params(jb.Ast, r0+row, mean, rstd);
          float4 g = *(const float4*)(jb.Ag  + k0 + c4);
          float4 bb= *(const float4*)(jb.Abt + k0 + c4);
          v.x = (v.x-mean)*rstd*g.x + bb.x;
          v.y = (v.y-mean)*rstd*g.y + bb.y;
          v.z = (v.z-mean)*rstd*g.z + bb.z;
          v.w = (v.w-mean)*rstd*g.w + bb.w;
        }
        f16x4 hv = { (f16)v.x, (f16)v.y, (f16)v.z, (f16)v.w };
        *(f16x4*)&As[row][c4] = hv;
      }
    }
#pragma unroll
    for (int p=0;p<BN/32;p++){
      int row = (tid>>3) + p*32, ch = tid & 7;
      *(uint4*)&Bs[row][ch*8] = *(const uint4*)(jb.BT + (size_t)(c0+row)*HDIM + k0 + ch*8);
    }
    __syncthreads();
#pragma unroll
    for (int kk=0;kk<2;kk++){
      f16x8 af[MI], bf[NI];
#pragma unroll
      for (int mi=0;mi<MI;mi++)
        af[mi] = *(const f16x8*)&As[wm*(BM/2)+mi*16+(lane&15)][kk*32 + 8*(lane>>4)];
#pragma unroll
      for (int ni=0;ni<NI;ni++)
        bf[ni] = *(const f16x8*)&Bs[wn*(BN/2)+ni*16+(lane&15)][kk*32 + 8*(lane>>4)];
#pragma unroll
      for (int mi=0;mi<MI;mi++)
#pragma unroll
        for (int ni=0;ni<NI;ni++)
          acc[mi][ni] = __builtin_amdgcn_mfma_f32_16x16x32_f16(af[mi], bf[ni], acc[mi][ni], 0,0,0);
    }
    __syncthreads();
  }

  if constexpr (EPI == 0){
    f16* C = (f16*)jb.C;
    const float sc = jb.scale;
#pragma unroll
    for (int mi=0;mi<MI;mi++)
#pragma unroll
      for (int ni=0;ni<NI;ni++)
#pragma unroll
        for (int r=0;r<4;r++){
          int row = r0 + wm*(BM/2) + mi*16 + 4*(lane>>4) + r;
          int col = c0 + wn*(BN/2) + ni*16 + (lane&15);
          C[(size_t)row*HDIM + col] = (f16)(acc[mi][ni][r] * sc);
        }
  } else {
    float* C = (float*)jb.C;
#pragma unroll
    for (int mi=0;mi<MI;mi++)
#pragma unroll
      for (int r=0;r<4;r++){
        int row = r0 + wm*(BM/2) + mi*16 + 4*(lane>>4) + r;
        float rmean=0.f, rrstd=0.f;
        if constexpr (RESMODE == 1){ ln_params(jb.Rst, row, rmean, rrstd); }
        float sv = 0.f, sq = 0.f;
#pragma unroll
        for (int ni=0;ni<NI;ni++){
          int col = c0 + wn*(BN/2) + ni*16 + (lane&15);
          float rv = jb.Res[(size_t)row*HDIM + col];
          if constexpr (RESMODE == 1) rv = (rv - rmean)*rrstd*jb.Rg[col] + jb.Rbt[col];
          float v = acc[mi][ni][r] + rv;
          C[(size_t)row*HDIM + col] = v;
          sv += v; sq += v*v;
        }
#pragma unroll
        for (int m=1;m<16;m<<=1){ sv += __shfl_xor(sv, m); sq += __shfl_xor(sq, m); }
        if ((lane & 15) == 0){
          atomicAdd(&jb.Ost[row*2+0], sv);
          atomicAdd(&jb.Ost[row*2+1], sq);
        }
      }
  }
}

// ---------------------------------------------------------------------------
// 64x64-tile GEMM, 512 thr, in-block split-K: waves 0-3 do k=[0,512),
// waves 4-7 k=[512,1024) in their own LDS buffers, then LDS cross-reduce and
// group-0 epilogue. 2 waves/SIMD (vs 1 for the 256-thr version) and the
// serial K-chain halves 16->8 barrier steps.
// ---------------------------------------------------------------------------
template<int AMODE,int EPI,int RESMODE>
__global__ __launch_bounds__(512)
void gemm64_k(JobPack jp){
  const Job jb = jp.j[blockIdx.z];
  __shared__ f16 As[2][64][72];
  __shared__ f16 Bs[2][64][72];
  const int tid = threadIdx.x;
  const int half = tid >> 8;          // K-group
  const int ht = tid & 255;
  const int lane = tid & 63;
  const int wv4 = ht >> 6;
  const int wm = wv4 >> 1, wn = wv4 & 1;
  const int r0 = blockIdx.y*64, c0 = blockIdx.x*64;
  f32x4 acc[2][2];
  const f32x4 fz = {0.f,0.f,0.f,0.f};
#pragma unroll
  for (int a=0;a<2;a++)
#pragma unroll
    for (int b=0;b<2;b++) acc[a][b]=fz;

  for (int ks=0; ks<8; ks++){
    const int k0 = half*512 + ks*64;
    if constexpr (AMODE == 2){
      const f16* Af = (const f16*)jb.A;
#pragma unroll
      for (int p=0;p<2;p++){
        int row=(ht>>3)+p*32, ch=ht&7;
        *(uint4*)&As[half][row][ch*8] = *(const uint4*)(Af + (size_t)(r0+row)*HDIM + k0 + ch*8);
      }
    } else {
      const float* Af = (const float*)jb.A;
#pragma unroll
      for (int p=0;p<4;p++){
        int row=(ht>>4)+p*16, c4=(ht&15)*4;
        float4 v = *(const float4*)(Af + (size_t)(r0+row)*HDIM + k0 + c4);
        if constexpr (AMODE == 1){
          float mean,rstd; ln_params(jb.Ast, r0+row, mean, rstd);
          float4 g = *(const float4*)(jb.Ag  + k0 + c4);
          float4 bb= *(const float4*)(jb.Abt + k0 + c4);
          v.x=(v.x-mean)*rstd*g.x+bb.x;
          v.y=(v.y-mean)*rstd*g.y+bb.y;
          v.z=(v.z-mean)*rstd*g.z+bb.z;
          v.w=(v.w-mean)*rstd*g.w+bb.w;
        }
        f16x4 hv={(f16)v.x,(f16)v.y,(f16)v.z,(f16)v.w};
        *(f16x4*)&As[half][row][c4]=hv;
      }
    }
#pragma unroll
    for (int p=0;p<2;p++){
      int row=(ht>>3)+p*32, ch=ht&7;
      *(uint4*)&Bs[half][row][ch*8] = *(const uint4*)(jb.BT + (size_t)(c0+row)*HDIM + k0 + ch*8);
    }
    __syncthreads();
#pragma unroll
    for (int kk=0;kk<2;kk++){
      f16x8 af[2], bf[2];
#pragma unroll
      for (int mi=0;mi<2;mi++)
        af[mi] = *(const f16x8*)&As[half][wm*32+mi*16+(lane&15)][kk*32+8*(lane>>4)];
#pragma unroll
      for (int ni=0;ni<2;ni++)
        bf[ni] = *(const f16x8*)&Bs[half][wn*32+ni*16+(lane&15)][kk*32+8*(lane>>4)];
#pragma unroll
      for (int mi=0;mi<2;mi++)
#pragma unroll
        for (int ni=0;ni<2;ni++)
          acc[mi][ni] = __builtin_amdgcn_mfma_f32_16x16x32_f16(af[mi], bf[ni], acc[mi][ni], 0,0,0);
    }
    __syncthreads();
  }

  // cross-half reduce: group 1 publishes into LDS (overlays As, 16.6KB < 18.4KB)
  float* red = (float*)&As[0][0][0];
  if (half == 1){
#pragma unroll
    for (int mi=0;mi<2;mi++)
#pragma unroll
      for (int ni=0;ni<2;ni++)
#pragma unroll
        for (int r=0;r<4;r++)
          red[(wm*32+mi*16+4*(lane>>4)+r)*65 + wn*32+ni*16+(lane&15)] = acc[mi][ni][r];
  }
  __syncthreads();
  if (half == 1) return;
#pragma unroll
  for (int mi=0;mi<2;mi++)
#pragma unroll
    for (int ni=0;ni<2;ni++)
#pragma unroll
      for (int r=0;r<4;r++)
        acc[mi][ni][r] += red[(wm*32+mi*16+4*(lane>>4)+r)*65 + wn*32+ni*16+(lane&15)];

  if constexpr (EPI == 0){
    f16* C = (f16*)jb.C;
    const float sc = jb.scale;
#pragma unroll
    for (int mi=0;mi<2;mi++)
#pragma unroll
      for (int ni=0;ni<2;ni++)
#pragma unroll
        for (int r=0;r<4;r++){
          int row = r0 + wm*32 + mi*16 + 4*(lane>>4) + r;
          int col = c0 + wn*32 + ni*16 + (lane&15);
          C[(size_t)row*HDIM + col] = (f16)(acc[mi][ni][r] * sc);
        }
  } else {
    float* C = (float*)jb.C;
#pragma unroll
    for (int mi=0;mi<2;mi++)
#pragma unroll
      for (int r=0;r<4;r++){
        int row = r0 + wm*32 + mi*16 + 4*(lane>>4) + r;
        float rmean=0.f, rrstd=0.f;
        if constexpr (RESMODE == 1){ ln_params(jb.Rst, row, rmean, rrstd); }
        float sv = 0.f, sq = 0.f;
#pragma unroll
        for (int ni=0;ni<2;ni++){
          int col = c0 + wn*32 + ni*16 + (lane&15);
          float rv = jb.Res[(size_t)row*HDIM + col];
          if constexpr (RESMODE == 1) rv = (rv - rmean)*rrstd*jb.Rg[col] + jb.Rbt[col];
          float v = acc[mi][ni][r] + rv;
          C[(size_t)row*HDIM + col] = v;
          sv += v; sq += v*v;
        }
#pragma unroll
        for (int m=1;m<16;m<<=1){ sv += __shfl_xor(sv, m); sq += __shfl_xor(sq, m); }
        if ((lane & 15) == 0){
          atomicAdd(&jb.Ost[row*2+0], sv);
          atomicAdd(&jb.Ost[row*2+1], sq);
        }
      }
  }
}

// ---------------------------------------------------------------------------
// Attention: one wave per (batch, head).
// ---------------------------------------------------------------------------
__global__ __launch_bounds__(64)
void attn_k(const f16* __restrict__ Q, const f16* __restrict__ K, const f16* __restrict__ V,
            f16* __restrict__ O, int L){
  __shared__ f16 Qs[32][72], Ks[32][72];
  __shared__ f16 Vt[64][56];
  __shared__ float S[32][33];
  __shared__ f16 Ps[32][56];
  const int l = threadIdx.x;
  const int b = blockIdx.x >> 4, hd = blockIdx.x & 15;
  {
    int row = l >> 1;
    int base = (l & 1) * 32;
#pragma unroll
    for (int v=0; v<4; v++){
      int off = base + v*8;
      *(uint4*)&Qs[row][off] = *(const uint4*)(Q + (size_t)(b*32+row)*HDIM + hd*64 + off);
      *(uint4*)&Ks[row][off] = *(const uint4*)(K + (size_t)(b*32+row)*HDIM + hd*64 + off);
    }
  }
  {
    int kk = l & 31, d0 = (l>>5)*32;
    f16 tmp[32];
    const uint4* vs = (const uint4*)(V + (size_t)(b*32+kk)*HDIM + hd*64 + d0);
    *(uint4*)&tmp[0]  = vs[0];
    *(uint4*)&tmp[8]  = vs[1];
    *(uint4*)&tmp[16] = vs[2];
    *(uint4*)&tmp[24] = vs[3];
#pragma unroll
    for (int jj=0;jj<32;jj++) Vt[d0+jj][kk] = tmp[jj];
  }
  __syncthreads();
  const f32x4 fz = {0.f,0.f,0.f,0.f};
  f32x4 sc[2][2];
#pragma unroll
  for (int a=0;a<2;a++)
#pragma unroll
    for (int c=0;c<2;c++) sc[a][c] = fz;
#pragma unroll
  for (int ks=0;ks<2;ks++){
    f16x8 qa[2], kb[2];
#pragma unroll
    for (int ti=0;ti<2;ti++) qa[ti]=*(const f16x8*)&Qs[16*ti+(l&15)][ks*32+8*(l>>4)];
#pragma unroll
    for (int tj=0;tj<2;tj++) kb[tj]=*(const f16x8*)&Ks[16*tj+(l&15)][ks*32+8*(l>>4)];
#pragma unroll
    for (int ti=0;ti<2;ti++)
#pragma unroll
      for (int tj=0;tj<2;tj++)
        sc[ti][tj]=__builtin_amdgcn_mfma_f32_16x16x32_f16(qa[ti],kb[tj],sc[ti][tj],0,0,0);
  }
#pragma unroll
  for (int ti=0;ti<2;ti++)
#pragma unroll
    for (int tj=0;tj<2;tj++)
#pragma unroll
      for (int r=0;r<4;r++)
        S[16*ti+4*(l>>4)+r][16*tj+(l&15)] = sc[ti][tj][r];
  __syncthreads();
  {
    int q = l & 31, ch = (l>>5)*16;
    bool vq = q < L;
    float mx = -3.0e38f;
#pragma unroll
    for (int c=0;c<16;c++){ int k=ch+c; if (k<L) mx = fmaxf(mx, S[q][k]); }
    mx = fmaxf(mx, __shfl_xor(mx, 32));
    float e[16]; float sum=0.f;
#pragma unroll
    for (int c=0;c<16;c++){
      int k=ch+c;
      float ev = (vq && k<L) ? __expf(S[q][k]-mx) : 0.0f;
      e[c]=ev; sum+=ev;
    }
    sum += __shfl_xor(sum, 32);
    float inv = vq ? (1.0f/sum) : 0.0f;
#pragma unroll
    for (int c=0;c<16;c++) Ps[q][ch+c] = (f16)(e[c]*inv);
  }
  __syncthreads();
  {
    f16x8 pa[2], vb[4];
#pragma unroll
    for (int ti=0;ti<2;ti++) pa[ti]=*(const f16x8*)&Ps[16*ti+(l&15)][8*(l>>4)];
#pragma unroll
    for (int tj=0;tj<4;tj++) vb[tj]=*(const f16x8*)&Vt[16*tj+(l&15)][8*(l>>4)];
    const f32x4 fz2 = {0.f,0.f,0.f,0.f};
#pragma unroll
    for (int ti=0;ti<2;ti++)
#pragma unroll
      for (int tj=0;tj<4;tj++){
        f32x4 o = __builtin_amdgcn_mfma_f32_16x16x32_f16(pa[ti],vb[tj],fz2,0,0,0);
#pragma unroll
        for (int r=0;r<4;r++){
          int row = b*32 + 16*ti + 4*(l>>4) + r;
          int col = hd*64 + 16*tj + (l&15);
          O[(size_t)row*HDIM + col] = (f16)o[r];
        }
      }
  }
}

// ---------------------------------------------------------------------------
// Skinny hf @ Wso GEMM, split-K 64-way -> partials[64][32][512].
// Block x==0 additionally folds the hf @ Wr dot (exact same LN-applied fp16
// hf tile already staged in As) into rbuf[b] via one atomic per (block,b).
// BSRC: 0 = fp16 pre-transposed WsoT [512][32768]; 1 = f32 Wso fallback.
// ---------------------------------------------------------------------------
template<int BSRC>
__global__ __launch_bounds__(256)
void wso_k(const float* __restrict__ X, const float* __restrict__ st,
           const float* __restrict__ g, const float* __restrict__ bt,
           const void* __restrict__ Wso_, const float* __restrict__ Wr,
           float* __restrict__ partials, float* __restrict__ rbuf){
  __shared__ f16 As[32][72];
  __shared__ f16 Bs[64][72];
  const int tid=threadIdx.x, lane=tid&63, wv=tid>>6;
  const int wm=wv>>1, wn=wv&1;
  const int n0 = blockIdx.x*64;
  const int kb = blockIdx.y;
  const f32x4 fz = {0.f,0.f,0.f,0.f};
  f32x4 acc0=fz, acc1=fz;
  float rsum = 0.f;
  for (int s8=0;s8<8;s8++){
    int kg0 = kb*512 + s8*64;
    int tt = kg0 >> 10, cb = kg0 & 1023;
#pragma unroll
    for (int p=0;p<2;p++){
      int brow=(tid>>4)+p*16, c4=(tid&15)*4;
      int grow = brow*32+tt;
      float4 v = *(const float4*)(X + (size_t)grow*HDIM + cb + c4);
      float mean,rstd; ln_params(st, grow, mean, rstd);
      float4 gg = *(const float4*)(g  + cb + c4);
      float4 bb = *(const float4*)(bt + cb + c4);
      v.x=(v.x-mean)*rstd*gg.x+bb.x;
      v.y=(v.y-mean)*rstd*gg.y+bb.y;
      v.z=(v.z-mean)*rstd*gg.z+bb.z;
      v.w=(v.w-mean)*rstd*gg.w+bb.w;
      f16x4 hv={(f16)v.x,(f16)v.y,(f16)v.z,(f16)v.w};
      *(f16x4*)&As[brow][c4]=hv;
    }
    if constexpr (BSRC == 0){
      const f16* WT = (const f16*)Wso_;
#pragma unroll
      for (int p=0;p<2;p++){
        int row=(tid>>3)+p*32, ch=tid&7;
        *(uint4*)&Bs[row][ch*8] = *(const uint4*)(WT + (size_t)(n0+row)*32768 + kg0 + ch*8);
      }
    } else {
      const float* W = (const float*)Wso_;
#pragma unroll
      for (int p=0;p<4;p++){
        int kk=(tid>>4)+p*16, n4=(tid&15)*4;
        float4 v = *(const float4*)(W + (size_t)(kg0+kk)*512 + n0 + n4);
        Bs[n4+0][kk]=(f16)v.x; Bs[n4+1][kk]=(f16)v.y;
        Bs[n4+2][kk]=(f16)v.z; Bs[n4+3][kk]=(f16)v.w;
      }
    }
    __syncthreads();
    if (blockIdx.x == 0){
      int b = tid>>3, e0 = (tid&7)*8;
#pragma unroll
      for (int e=0;e<8;e++) rsum += (float)As[b][e0+e] * Wr[kg0+e0+e];
    }
#pragma unroll
    for (int kk2=0;kk2<2;kk2++){
      f16x8 a0=*(const f16x8*)&As[wm*16+(lane&15)][kk2*32+8*(lane>>4)];
      f16x8 b0=*(const f16x8*)&Bs[wn*32+ 0+(lane&15)][kk2*32+8*(lane>>4)];
      f16x8 b1=*(const f16x8*)&Bs[wn*32+16+(lane&15)][kk2*32+8*(lane>>4)];
      acc0=__builtin_amdgcn_mfma_f32_16x16x32_f16(a0,b0,acc0,0,0,0);
      acc1=__builtin_amdgcn_mfma_f32_16x16x32_f16(a0,b1,acc1,0,0,0);
    }
    __syncthreads();
  }
#pragma unroll
  for (int r=0;r<4;r++){
    int brow = wm*16 + 4*(lane>>4) + r;
    int c_0 = n0 + wn*32 + 0 + (lane&15);
    int c_1 = n0 + wn*32 + 16 + (lane&15);
    partials[(size_t)kb*16384 + brow*512 + c_0] = acc0[r];
    partials[(size_t)kb*16384 + brow*512 + c_1] = acc1[r];
  }
  if (blockIdx.x == 0){
    rsum += __shfl_xor(rsum, 1);
    rsum += __shfl_xor(rsum, 2);
    rsum += __shfl_xor(rsum, 4);
    if ((tid & 7) == 0) atomicAdd(&rbuf[tid>>3], rsum);
  }
}

// ---------------------------------------------------------------------------
// Finalize: reduce Wso partials over 64 kb (coalesced across 16384 threads),
// relu -> out + sbuf; threads 0-31 of block 0 write r = sigmoid(rbuf[b]).
// ---------------------------------------------------------------------------
__global__ __launch_bounds__(256)
void finalize_k(const float* __restrict__ partials, const float* __restrict__ rbuf,
                float* __restrict__ out, float* __restrict__ sbuf, int iter){
  const int idx = blockIdx.x*256 + threadIdx.x;   // 0..16383
  const int b = idx >> 9, c = idx & 511;
  float s = 0.f;
  for (int ks=0; ks<64; ks++) s += partials[(size_t)ks*16384 + idx];
  s = fmaxf(s, 0.f);
  out[256 + (size_t)(b*TAI + iter)*512 + c] = s;
  sbuf[idx] = s;
  if (idx < 32) out[idx*TAI + iter] = 1.0f/(1.0f+__expf(-rbuf[idx]));
}

// ---------------------------------------------------------------------------
// h0 = tokens + pe (valid rows), inline action-embed for row pos_a.
// ---------------------------------------------------------------------------
__global__ __launch_bounds__(256)
void h0_k(float* __restrict__ tokens, const float* __restrict__ pe,
          const float* __restrict__ a_list, const float* __restrict__ Wa,
          float* __restrict__ h0, int iter){
  const int r = blockIdx.x;
  const int b = r >> 5, t5 = r & 31;
  const int pos_a = 17 + 2*iter, L = pos_a + 1;
  const int c4 = threadIdx.x * 4;
  if (t5 >= L){
    float4 z = make_float4(0.f,0.f,0.f,0.f);
    *(float4*)&h0[(size_t)r*HDIM + c4] = z;
    return;
  }
  if (t5 == pos_a){
    __shared__ float al[64];
    if (threadIdx.x < 64) al[threadIdx.x] = a_list[(size_t)(b*TAI + iter)*64 + threadIdx.x];
    __syncthreads();
    float s0=0.f,s1=0.f,s2=0.f,s3=0.f;
    for (int k=0;k<64;k++){
      float av = al[k];
      const float* wr = Wa + (size_t)k*HDIM + c4;
      s0 += av*wr[0]; s1 += av*wr[1]; s2 += av*wr[2]; s3 += av*wr[3];
    }
    s0=fmaxf(s0,0.f); s1=fmaxf(s1,0.f); s2=fmaxf(s2,0.f); s3=fmaxf(s3,0.f);
    *(float4*)&tokens[(size_t)r*HDIM + c4] = make_float4(s0,s1,s2,s3);
    const float4 pv = *(const float4*)&pe[(size_t)t5*HDIM + c4];
    *(float4*)&h0[(size_t)r*HDIM + c4] = make_float4(s0+pv.x, s1+pv.y, s2+pv.z, s3+pv.w);
  } else {
    const float4 tv = *(const float4*)&tokens[(size_t)r*HDIM + c4];
    const float4 pv = *(const float4*)&pe[(size_t)t5*HDIM + c4];
    *(float4*)&h0[(size_t)r*HDIM + c4] = make_float4(tv.x+pv.x, tv.y+pv.y, tv.z+pv.z, tv.w+pv.w);
  }
}

// ---------------------------------------------------------------------------
// Small fp32 embed GEMM: out[row_map(ar)] = relu(A[ar] @ W).
// ---------------------------------------------------------------------------
__global__ __launch_bounds__(256)
void embed_k(const float* __restrict__ A, int K, const float* __restrict__ W,
             float* __restrict__ outb, int tpg, int str, int off){
  __shared__ float as[8][512];
  const int r0 = blockIdx.x*8;
  const int t = threadIdx.x;
  for (int rr=0;rr<8;rr++)
    for (int k=t;k<K;k+=256) as[rr][k] = A[(size_t)(r0+rr)*K + k];
  __syncthreads();
  const int c = blockIdx.y*256 + t;
  float acc[8];
#pragma unroll
  for (int rr=0;rr<8;rr++) acc[rr]=0.f;
  for (int k=0;k<K;k++){
    float wv = W[(size_t)k*HDIM + c];
#pragma unroll
    for (int rr=0;rr<8;rr++) acc[rr] += as[rr][k]*wv;
  }
#pragma unroll
  for (int rr=0;rr<8;rr++){
    int ar = r0+rr;
    int orow = (ar/tpg)*32 + (ar%tpg)*str + off;
    outb[(size_t)orow*HDIM + c] = fmaxf(acc[rr], 0.f);
  }
}

// ---------------------------------------------------------------------------
// fp32 [K][N] -> fp16 [N][K] transpose-convert
// ---------------------------------------------------------------------------
__global__ __launch_bounds__(256)
void transp_k(const float* __restrict__ in, f16* __restrict__ outp, int K, int N){
  __shared__ float tile[32][33];
  const int n0 = blockIdx.x*32, k0 = blockIdx.y*32;
  const float* ip = in + (size_t)blockIdx.z*K*N;
  f16* op = outp + (size_t)blockIdx.z*K*N;
  const int tx = threadIdx.x & 31, ty = threadIdx.x >> 5;
#pragma unroll
  for (int p=0;p<4;p++){ int kk=ty+p*8; tile[kk][tx] = ip[(size_t)(k0+kk)*N + n0+tx]; }
  __syncthreads();
#pragma unroll
  for (int p=0;p<4;p++){ int nn=ty+p*8; op[(size_t)(n0+nn)*K + k0+tx] = (f16)tile[tx][nn]; }
}

__global__ __launch_bounds__(256)
void pe_k(float* __restrict__ pe){
  int idx = blockIdx.x*256 + threadIdx.x;
  int t = idx >> 10, ii = idx & 1023;
  double ang = (double)t / pow(10000.0, (double)(2*(ii/2)) / 1024.0);
  pe[idx] = (float)(((ii & 1)==0) ? sin(ang) : cos(ang));
}

// ---------------------------------------------------------------------------
extern "C" void kernel_launch(void* const* d_in, const int* in_sizes, int n_in,
                              void* d_out, int out_size, void* d_ws, size_t ws_size,
                              hipStream_t stream){
  (void)in_sizes; (void)n_in; (void)out_size;
  const float* hist_s=(const float*)d_in[0];
  const float* hist_a=(const float*)d_in[1];
  const float* s_in  =(const float*)d_in[2];
  const float* a_list=(const float*)d_in[3];
  const float* Ws =(const float*)d_in[4];
  const float* Wa =(const float*)d_in[5];
  const float* Wq =(const float*)d_in[6];
  const float* Wk =(const float*)d_in[7];
  const float* Wv =(const float*)d_in[8];
  const float* Wo =(const float*)d_in[9];
  const float* Wfc=(const float*)d_in[10];
  const float* ln1g=(const float*)d_in[11];
  const float* ln1b=(const float*)d_in[12];
  const float* ln2g=(const float*)d_in[13];
  const float* ln2b=(const float*)d_in[14];
  const float* Wr =(const float*)d_in[15];
  const float* Wso=(const float*)d_in[16];
  float* out=(float*)d_out;

  char* wp=(char*)d_ws;
  auto alloc=[&](size_t bytes)->char*{ char* p=wp; wp += (bytes + 255) & ~(size_t)255; return p; };
  const size_t MB = 1024*1024;
  const size_t MM = 1024*1024;

  float* tokens =(float*)alloc(4*MB);                   // zeroed
  float* stats  =(float*)alloc(64*2048*sizeof(float));  // zeroed
  float* rbuf   =(float*)alloc(8*32*sizeof(float));     // zeroed (Wr-dot partials)
  float* pe     =(float*)alloc(32*1024*sizeof(float));
  float* h0     =(float*)alloc(4*MB);
  float* hout[4]; for(int j=0;j<4;j++) hout[j]=(float*)alloc(4*MB);
  float* x1     =(float*)alloc(4*MB);
  f16* Q16[4]; for(int j=0;j<4;j++) Q16[j]=(f16*)alloc(2*MB);
  f16* K16[4]; for(int j=0;j<4;j++) K16[j]=(f16*)alloc(2*MB);
  f16* V16 =(f16*)alloc(2*MB);
  f16* AT16=(f16*)alloc(2*MB);
  f16* WqT =(f16*)alloc(8*MB);
  f16* WkT =(f16*)alloc(8*MB);
  f16* WvT =(f16*)alloc(8*MB);
  f16* WoT =(f16*)alloc(8*MB);
  f16* WfcT=(f16*)alloc(8*MB);
  float* partials=(float*)alloc((size_t)64*32*512*sizeof(float));
  float* sbuf=(float*)alloc(32*512*sizeof(float));
  f16* WsoT=(f16*)alloc((size_t)512*32768*sizeof(f16)); // 32 MB, optional
  const bool big = (size_t)(wp - (char*)d_ws) <= ws_size; // deterministic per process

  // zero tokens + stats + rbuf (contiguous up to pe)
  hipMemsetAsync(tokens, 0, (size_t)((char*)pe - (char*)tokens), stream);

  pe_k<<<128,256,0,stream>>>(pe);
  transp_k<<<dim3(32,32,4),256,0,stream>>>(Wq,  WqT, 1024,1024);
  transp_k<<<dim3(32,32,4),256,0,stream>>>(Wk,  WkT, 1024,1024);
  transp_k<<<dim3(32,32,4),256,0,stream>>>(Wv,  WvT, 1024,1024);
  transp_k<<<dim3(32,32,4),256,0,stream>>>(Wo,  WoT, 1024,1024);
  transp_k<<<dim3(32,32,4),256,0,stream>>>(Wfc, WfcT,1024,1024);
  if (big) transp_k<<<dim3(16,1024,1),256,0,stream>>>(Wso, WsoT, 32768, 512);
  embed_k<<<dim3(32,4),256,0,stream>>>(hist_s,512,Ws,tokens,8,2,0);
  embed_k<<<dim3(32,4),256,0,stream>>>(hist_a, 64,Wa,tokens,8,2,1);
  embed_k<<<dim3(4,4),256,0,stream>>>(s_in,  512,Ws,tokens,1,0,16);

  auto st1=[&](int i,int j)->float*{ return stats + ((size_t)(i*4+j)*2+0)*2048; };
  auto st2=[&](int i,int j)->float*{ return stats + ((size_t)(i*4+j)*2+1)*2048; };

  auto mkj=[&](const void*A,const float*Ast,const float*Ag,const float*Abt,
               const f16*BT,void*C,float scale)->Job{
    Job q{}; q.A=A; q.Ast=Ast; q.Ag=Ag; q.Abt=Abt; q.BT=BT; q.C=C; q.scale=scale; return q;
  };
  auto mkj2=[&](const void*A,const float*Ast,const float*Ag,const float*Abt,
                const f16*BT,void*C,const float*Res,const float*Rst,const float*Rg,
                const float*Rbt,float*Ost)->Job{
    Job q{}; q.A=A; q.Ast=Ast; q.Ag=Ag; q.Abt=Abt; q.BT=BT; q.C=C;
    q.Res=Res; q.Rst=Rst; q.Rg=Rg; q.Rbt=Rbt; q.Ost=Ost; q.scale=1.f; return q;
  };

  for (int i=0;i<8;i++){
    const int pos_a = 17 + 2*i, L = pos_a + 1;
    h0_k<<<1024,256,0,stream>>>(tokens, pe, a_list, Wa, h0, i);

    if (i>0){
      JobPack jp{};
      for (int j=0;j<4;j++){
        jp.j[2*j+0]=mkj(hout[j], st2(i-1,j), ln2g+j*1024, ln2b+j*1024,
                        WqT+(size_t)j*MM, Q16[j], 0.125f);
        jp.j[2*j+1]=mkj(hout[j], st2(i-1,j), ln2g+j*1024, ln2b+j*1024,
                        WkT+(size_t)j*MM, K16[j], 1.0f);
      }
      gemm_k<128,128,1,0,0><<<dim3(8,8,8),256,0,stream>>>(jp);
    }

    for (int j=0;j<4;j++){
      const float* Ain  = (j==0)? h0 : hout[j-1];
      const float* Ast  = (j==0)? nullptr : st2(i,j-1);
      const float* Ag   = (j==0)? nullptr : ln2g+(j-1)*1024;
      const float* Abt  = (j==0)? nullptr : ln2b+(j-1)*1024;

      if (i==0){
        JobPack jp{};
        jp.j[0]=mkj(Ain,Ast,Ag,Abt, WqT+(size_t)j*MM, Q16[j], 0.125f);
        jp.j[1]=mkj(Ain,Ast,Ag,Abt, WkT+(size_t)j*MM, K16[j], 1.0f);
        jp.j[2]=mkj(Ain,Ast,Ag,Abt, WvT+(size_t)j*MM, V16,    1.0f);
        if (j==0) gemm64_k<0,0,0><<<dim3(16,16,3),512,0,stream>>>(jp);
        else      gemm64_k<1,0,0><<<dim3(16,16,3),512,0,stream>>>(jp);
      } else {
        JobPack jp{};
        jp.j[0]=mkj(Ain,Ast,Ag,Abt, WvT+(size_t)j*MM, V16, 1.0f);
        if (j==0) gemm64_k<0,0,0><<<dim3(16,16,1),512,0,stream>>>(jp);
        else      gemm64_k<1,0,0><<<dim3(16,16,1),512,0,stream>>>(jp);
      }

      attn_k<<<512,64,0,stream>>>(Q16[j], K16[j], V16, AT16, L);

      { // Wo projection + residual(h_in) + LN1 stats
        JobPack jo{};
        jo.j[0]=mkj2(AT16, nullptr,nullptr,nullptr, WoT+(size_t)j*MM, x1,
                     Ain, Ast, Ag, Abt, st1(i,j));
        if (j==0) gemm64_k<2,1,0><<<dim3(16,16,1),512,0,stream>>>(jo);
        else      gemm64_k<2,1,1><<<dim3(16,16,1),512,0,stream>>>(jo);
      }
      { // FC + residual(LN1(x1)) + LN2 stats
        JobPack jf{};
        jf.j[0]=mkj2(x1, st1(i,j), ln1g+j*1024, ln1b+j*1024, WfcT+(size_t)j*MM, hout[j],
                     x1, st1(i,j), ln1g+j*1024, ln1b+j*1024, st2(i,j));
        gemm64_k<1,1,1><<<dim3(16,16,1),512,0,stream>>>(jf);
      }
    }

    if (big) wso_k<0><<<dim3(8,64),256,0,stream>>>(hout[3], st2(i,3), ln2g+3*1024, ln2b+3*1024,
                                                   WsoT, Wr, partials, rbuf+i*32);
    else     wso_k<1><<<dim3(8,64),256,0,stream>>>(hout[3], st2(i,3), ln2g+3*1024, ln2b+3*1024,
                                                   Wso,  Wr, partials, rbuf+i*32);
    finalize_k<<<64,256,0,stream>>>(partials, rbuf+i*32, out, sbuf, i);
    if (i < 7){
      embed_k<<<dim3(4,4),256,0,stream>>>(sbuf, 512, Ws, tokens, 1, 0, pos_a+1);
    }
  }
}